// Round 9
// baseline (390.422 us; speedup 1.0000x reference)
//
#include <hip/hip_runtime.h>
#include <math.h>

// NanoRAG: cosine-sim retrieval + top-8 + softmax fusion.
// K0: normalize queries, split into bf16 hi/lo -> ws.qh/ws.ql
// K1: persistent 256 blocks x 512 threads. Docs streamed LINEARLY (full
//     1536-B rows, contiguous 1-KB spans per wave) in 32-doc chunks,
//     depth-2 register prefetch + counted vmcnt, RNE-split once to
//     double-buffered full-K LDS planes. q fragments in regs (loaded once).
//     8 waves = 4 q-tiles x 2 doc-strips. Raw s_barriers (no vmcnt drain).
//     Per-128-doc-slab top-8 -> ws.partial [q][2048][8].
// K2a: partial merge 2048 lists -> 8 chunk lists per q (512 blocks)
// K2b: final merge 64 -> top-8, softmax, gather+fuse -> d_out
//
// d_out layout (fp32): fused[64*384], scores[64*8], idx[64*8]

#define EMBED 384
#define NDOCS 262144
#define BATCH 64
#define TOPK 8
#define NBLK 2048             // 128-doc slabs
#define EPSN 1e-8f
#define SCW 132

#define ST 784                // LDS plane row stride (bytes), 16-aligned
#define PLANE 25088u          // 32 * 784
#define BUFSZ 50176u          // hi+lo per buffer
#define S_OFF 100352u         // score tile offset
#define RN_OFF 134144u        // rnorm offset
#define LDS_TOT 134656

typedef __attribute__((ext_vector_type(8))) short bf16x8;
typedef __attribute__((ext_vector_type(4))) float f32x4;

#define INS8(s_, i_) do {                                                     \
    if ((s_) > ts[7] || ((s_) == ts[7] && (i_) < ti[7])) {                    \
        ts[7] = (s_); ti[7] = (i_);                                           \
        _Pragma("unroll")                                                     \
        for (int r_ = 7; r_ > 0; --r_) {                                      \
            bool sw_ = (ts[r_] > ts[r_-1]) ||                                 \
                       (ts[r_] == ts[r_-1] && ti[r_] < ti[r_-1]);             \
            float a_ = ts[r_-1]; int b_ = ti[r_-1];                           \
            ts[r_-1] = sw_ ? ts[r_] : a_;  ti[r_-1] = sw_ ? ti[r_] : b_;      \
            ts[r_]   = sw_ ? a_ : ts[r_];  ti[r_]   = sw_ ? b_ : ti[r_];      \
        }                                                                     \
    }                                                                         \
} while (0)

template<int OFF>
__device__ __forceinline__ int4 gload_s(unsigned voff, const void* sbase) {
    int4 r;
    asm volatile("global_load_dwordx4 %0, %1, %2 offset:%3"
                 : "=v"(r) : "v"(voff), "s"(sbase), "i"(OFF) : "memory");
    return r;
}

template<int OFF>
__device__ __forceinline__ int4 dsread16(unsigned a) {
    int4 r;
    asm volatile("ds_read_b128 %0, %1 offset:%2" : "=v"(r) : "v"(a), "i"(OFF) : "memory");
    return r;
}

// Manual RNE bf16 split: f ~= hi + lo, |err| <= 2^-18|f|. PROVEN numerics
// (R2/R3/R6/R7 absmax 3e-5). Do NOT use v_cvt_pk_bf16_f32 (R4 index flip).
#define SPB(F, H, O) {                                                        \
    unsigned u_ = __float_as_uint(F);                                         \
    H = (u_ + 0x7fffu + ((u_ >> 16) & 1u)) >> 16;                             \
    float r_ = (F) - __uint_as_float((H) << 16);                              \
    unsigned v_ = __float_as_uint(r_);                                        \
    O = (v_ + 0x7fffu + ((v_ >> 16) & 1u)) >> 16;                             \
}

#define SPLIT4(ARR, C) {                                                      \
    f32x4 f_ = *(f32x4*)&ARR[C];                                              \
    unsigned h0_, h1_, h2_, h3_, o0_, o1_, o2_, o3_;                          \
    SPB(f_[0], h0_, o0_); SPB(f_[1], h1_, o1_);                               \
    SPB(f_[2], h2_, o2_); SPB(f_[3], h3_, o3_);                               \
    sh[C].x = (h0_ & 0xffffu) | (h1_ << 16);                                  \
    sh[C].y = (h2_ & 0xffffu) | (h3_ << 16);                                  \
    sl[C].x = (o0_ & 0xffffu) | (o1_ << 16);                                  \
    sl[C].y = (o2_ & 0xffffu) | (o3_ << 16);                                  \
}

__global__ void qprep_kernel(const float* __restrict__ q,
                             unsigned short* __restrict__ qh,
                             unsigned short* __restrict__ ql) {
    const int row = blockIdx.x;
    const int lane = threadIdx.x;
    float v[6];
    float s = 0.f;
#pragma unroll
    for (int i = 0; i < 6; ++i) {
        v[i] = q[row * EMBED + lane + 64 * i];
        s = fmaf(v[i], v[i], s);
    }
#pragma unroll
    for (int off = 32; off > 0; off >>= 1) s += __shfl_xor(s, off);
    float rinv = 1.0f / (sqrtf(s) + EPSN);
#pragma unroll
    for (int i = 0; i < 6; ++i) {
        float f = v[i] * rinv;
        unsigned h, lo;
        SPB(f, h, lo);
        qh[row * EMBED + lane + 64 * i] = (unsigned short)h;
        ql[row * EMBED + lane + 64 * i] = (unsigned short)lo;
    }
}

__global__ __launch_bounds__(512, 2) void score_topk_kernel(
        const float* __restrict__ docs,
        const unsigned short* __restrict__ qh,
        const unsigned short* __restrict__ ql,
        float* __restrict__ pscore, int* __restrict__ pidx) {
    __shared__ __align__(16) char smem[LDS_TOT];
    float* S  = (float*)(smem + S_OFF);
    float* RN = (float*)(smem + RN_OFF);
    float* Ls = (float*)smem;            // epilogue lists overlay dead planes
    int*   Li = (int*)(smem + 16384);

    const int tid = threadIdx.x;
    const int l   = tid & 63;
    const int wv  = tid >> 6;            // 8 waves
    const int qt  = wv & 3;              // q-tile
    const int ds  = wv >> 2;             // doc-strip (16 docs)
    const int rowl = l & 15;
    const int ksub = l >> 4;
    const int D0 = blockIdx.x * 1024;    // this block's 1024 docs
    const unsigned bse = (unsigned)(uintptr_t)smem;

    // ---- q fragments: tile qt, all 384 k, in registers (loaded once) ----
    int4 qf[12][2];
    {
        unsigned vq = (unsigned)((qt * 16 + rowl) * 768 + ksub * 16);
#pragma unroll
        for (int kb = 0; kb < 12; ++kb) {
            qf[kb][0] = gload_s<0>(vq + kb * 64, qh);
            qf[kb][1] = gload_s<0>(vq + kb * 64, ql);
        }
    }

    // ---- linear staging addresses: flat idx f = i*512 + tid over 48 KB ----
    unsigned voff[6], dsw[6];
#pragma unroll
    for (int i = 0; i < 6; ++i) {
        unsigned f = (unsigned)(i * 512 + tid);
        unsigned row = (f * 10923u) >> 20;      // f / 96 (exact for f < 3072)
        unsigned rem = f - row * 96u;
        voff[i] = f * 16u;                      // byte offset within chunk
        dsw[i]  = row * ST + rem * 8u;          // within-plane LDS offset
    }
    const char* cbase = (const char*)docs + (size_t)D0 * 1536;

    // ds_read fragment base (buf0); buf1 = +BUFSZ
    const unsigned hb0 = bse + (unsigned)((ds * 16 + rowl) * ST + ksub * 16);
    const unsigned hb1 = hb0 + BUFSZ;

    f32x4 acc[4];
#pragma unroll
    for (int s = 0; s < 4; ++s) acc[s] = (f32x4){0.f, 0.f, 0.f, 0.f};
    float nacc[4] = {0.f, 0.f, 0.f, 0.f};

    int4 ldA[6], ldB[6];
    uint2 sh[6], sl[6];

    // prologue: chunk 0 -> A, chunk 1 -> B; wait q + chunk0 (leave B's 6)
#pragma unroll
    for (int i = 0; i < 6; ++i) ldA[i] = gload_s<0>(voff[i], cbase);
#pragma unroll
    for (int i = 0; i < 6; ++i) ldB[i] = gload_s<0>(voff[i], cbase + 49152);
    asm volatile("s_waitcnt vmcnt(6)" ::: "memory");
    __builtin_amdgcn_sched_barrier(0);
#pragma unroll
    for (int i = 0; i < 6; ++i) SPLIT4(ldA, i);

#pragma unroll 1
    for (int slab = 0; slab < 8; ++slab) {
#pragma unroll
        for (int cc = 0; cc < 4; ++cc) {
            const int c = slab * 4 + cc;
            // ---- write chunk c (from sh/sl) into buf cc&1 ----
            __builtin_amdgcn_s_barrier();     // prior reads of this buf done
            {
                char* wb = smem + (unsigned)((cc & 1) ? BUFSZ : 0u);
#pragma unroll
                for (int i = 0; i < 6; ++i) {
                    *(uint2*)(wb + dsw[i]) = sh[i];
                    *(uint2*)(wb + PLANE + dsw[i]) = sl[i];
                }
            }
            asm volatile("s_waitcnt lgkmcnt(0)" ::: "memory");
            __builtin_amdgcn_s_barrier();     // tile c visible

            // ---- issue chunk c+2 into the set freed by chunk c ----
            if (cc < 2 || slab < 7) {
                const char* nb = cbase + (size_t)(c + 2) * 49152;
                if ((cc & 1) == 0) {
#pragma unroll
                    for (int i = 0; i < 6; ++i) ldA[i] = gload_s<0>(voff[i], nb);
                } else {
#pragma unroll
                    for (int i = 0; i < 6; ++i) ldB[i] = gload_s<0>(voff[i], nb);
                }
            }

            // ---- compute chunk c: 12 kb x {2 ds_read + 3 MFMA} ----
            {
                const unsigned hb = (cc & 1) ? hb1 : hb0;
#pragma unroll
                for (int kb = 0; kb < 12; ++kb) {
                    int4 bhv = dsread16<0>(hb + kb * 64);
                    int4 blv = dsread16<25088>(hb + kb * 64);
                    asm volatile("s_waitcnt lgkmcnt(0)" ::: "memory");
                    __builtin_amdgcn_sched_barrier(0);
                    bf16x8 bh = *(bf16x8*)&bhv, bl = *(bf16x8*)&blv;
                    if (qt == 0) {            // norm from hi+lo reconstruction
                        float nsum = nacc[cc];
#pragma unroll
                        for (int e = 0; e < 8; ++e) {
                            float H = __uint_as_float(((unsigned)(unsigned short)bh[e]) << 16);
                            float L = __uint_as_float(((unsigned)(unsigned short)bl[e]) << 16);
                            float fv = H + L;
                            nsum = fmaf(fv, fv, nsum);
                        }
                        nacc[cc] = nsum;
                    }
                    acc[cc] = __builtin_amdgcn_mfma_f32_16x16x32_bf16(*(bf16x8*)&qf[kb][0], bh, acc[cc], 0, 0, 0);
                    acc[cc] = __builtin_amdgcn_mfma_f32_16x16x32_bf16(*(bf16x8*)&qf[kb][1], bh, acc[cc], 0, 0, 0);
                    acc[cc] = __builtin_amdgcn_mfma_f32_16x16x32_bf16(*(bf16x8*)&qf[kb][0], bl, acc[cc], 0, 0, 0);
                }
            }

            // ---- wait chunk c+1, split it ----
            if (!(slab == 7 && cc == 3)) {
                if (slab == 7 && cc == 2) {
                    asm volatile("s_waitcnt vmcnt(0)" ::: "memory");
                } else {
                    asm volatile("s_waitcnt vmcnt(6)" ::: "memory");
                }
                __builtin_amdgcn_sched_barrier(0);
                if ((cc & 1) == 0) {
#pragma unroll
                    for (int i = 0; i < 6; ++i) SPLIT4(ldB, i);
                } else {
#pragma unroll
                    for (int i = 0; i < 6; ++i) SPLIT4(ldA, i);
                }
            }
        }

        // ================= slab epilogue (128 docs) =================
        const int slab_g = blockIdx.x * 8 + slab;
        if (qt == 0) {                        // waves 0,4: finish norms
#pragma unroll
            for (int cc = 0; cc < 4; ++cc) {
                float t = nacc[cc];
                t += __shfl_xor(t, 16);
                t += __shfl_xor(t, 32);
                if (l < 16) RN[cc * 32 + ds * 16 + l] = 1.0f / (sqrtf(t) + EPSN);
                nacc[cc] = 0.f;
            }
        }
        asm volatile("s_waitcnt lgkmcnt(0)" ::: "memory");
        __builtin_amdgcn_s_barrier();

        // S write (normalized scores), disjoint per wave
#pragma unroll
        for (int cc = 0; cc < 4; ++cc) {
            int col = cc * 32 + ds * 16 + rowl;
            float rn = RN[col];
#pragma unroll
            for (int j = 0; j < 4; ++j)
                S[(qt * 16 + ksub * 4 + j) * SCW + col] = acc[cc][j] * rn;
            acc[cc] = (f32x4){0.f, 0.f, 0.f, 0.f};
        }
        asm volatile("s_waitcnt lgkmcnt(0)" ::: "memory");
        __builtin_amdgcn_s_barrier();

        // scan: thread t -> query t&63, octant t>>6 (16 docs, staggered)
        {
            float ts[8]; int ti[8];
#pragma unroll
            for (int r = 0; r < 8; ++r) { ts[r] = -3.402823466e38f; ti[r] = 0x7fffffff; }
            const int q = tid & 63, oct = tid >> 6;
            for (int ii = 0; ii < 16; ++ii) {
                int d = oct * 16 + ((ii + q) & 15);
                float sc = S[q * SCW + d];
                INS8(sc, D0 + slab * 128 + d);
            }
#pragma unroll
            for (int r = 0; r < 8; ++r) {
                Ls[(oct * 64 + q) * 8 + r] = ts[r];
                Li[(oct * 64 + q) * 8 + r] = ti[r];
            }
        }
        asm volatile("s_waitcnt lgkmcnt(0)" ::: "memory");
        __builtin_amdgcn_s_barrier();

        if (tid < 64) {                       // merge 8 octant lists
            float ts[8]; int ti[8];
#pragma unroll
            for (int r = 0; r < 8; ++r) { ts[r] = -3.402823466e38f; ti[r] = 0x7fffffff; }
            for (int o2 = 0; o2 < 8; ++o2) {
#pragma unroll
                for (int r = 0; r < 8; ++r) {
                    float s2 = Ls[(o2 * 64 + tid) * 8 + r];
                    int i2 = Li[(o2 * 64 + tid) * 8 + r];
                    INS8(s2, i2);
                }
            }
            size_t o = ((size_t)tid * NBLK + slab_g) * TOPK;
            *(float4*)&pscore[o]     = make_float4(ts[0], ts[1], ts[2], ts[3]);
            *(float4*)&pscore[o + 4] = make_float4(ts[4], ts[5], ts[6], ts[7]);
            *(int4*)&pidx[o]     = make_int4(ti[0], ti[1], ti[2], ti[3]);
            *(int4*)&pidx[o + 4] = make_int4(ti[4], ti[5], ti[6], ti[7]);
        }
        // next iteration's top barrier protects list region before reuse
    }
}

// stage A: block (q, c) merges lists c*256..c*256+255 -> one top-8 chunk list
__global__ __launch_bounds__(256) void merge_a_kernel(
        const float* __restrict__ pscore, const int* __restrict__ pidx,
        float* __restrict__ cs, int* __restrict__ ci) {
    const int q = blockIdx.x >> 3;
    const int c = blockIdx.x & 7;
    const int tid = threadIdx.x;
    __shared__ float ls[2048];
    __shared__ int   li[2048];
    __shared__ float ls2[512];
    __shared__ int   li2[512];
    __shared__ float ls3[64];
    __shared__ int   li3[64];

    {
        size_t o = ((size_t)q * NBLK + c * 256 + tid) * TOPK;
        float4 s0 = *(const float4*)&pscore[o];
        float4 s1 = *(const float4*)&pscore[o + 4];
        int4 i0 = *(const int4*)&pidx[o];
        int4 i1 = *(const int4*)&pidx[o + 4];
        ls[tid * 8 + 0] = s0.x; ls[tid * 8 + 1] = s0.y;
        ls[tid * 8 + 2] = s0.z; ls[tid * 8 + 3] = s0.w;
        ls[tid * 8 + 4] = s1.x; ls[tid * 8 + 5] = s1.y;
        ls[tid * 8 + 6] = s1.z; ls[tid * 8 + 7] = s1.w;
        li[tid * 8 + 0] = i0.x; li[tid * 8 + 1] = i0.y;
        li[tid * 8 + 2] = i0.z; li[tid * 8 + 3] = i0.w;
        li[tid * 8 + 4] = i1.x; li[tid * 8 + 5] = i1.y;
        li[tid * 8 + 6] = i1.z; li[tid * 8 + 7] = i1.w;
    }
    __syncthreads();

    float ts[8]; int ti[8];
    if (tid < 64) {
#pragma unroll
        for (int r = 0; r < 8; ++r) { ts[r] = -3.402823466e38f; ti[r] = 0x7fffffff; }
        for (int e = 0; e < 32; ++e) {
            int k = tid + e * 64;
            float s = ls[k]; int gi = li[k];
            INS8(s, gi);
        }
#pragma unroll
        for (int r = 0; r < 8; ++r) { ls2[tid * 8 + r] = ts[r]; li2[tid * 8 + r] = ti[r]; }
    }
    __syncthreads();
    if (tid < 8) {
#pragma unroll
        for (int r = 0; r < 8; ++r) { ts[r] = -3.402823466e38f; ti[r] = 0x7fffffff; }
        for (int e = 0; e < 64; ++e) {
            int k = tid + e * 8;
            float s = ls2[k]; int gi = li2[k];
            INS8(s, gi);
        }
#pragma unroll
        for (int r = 0; r < 8; ++r) { ls3[tid * 8 + r] = ts[r]; li3[tid * 8 + r] = ti[r]; }
    }
    __syncthreads();
    if (tid == 0) {
#pragma unroll
        for (int r = 0; r < 8; ++r) { ts[r] = -3.402823466e38f; ti[r] = 0x7fffffff; }
        for (int e = 0; e < 64; ++e) {
            float s = ls3[e]; int gi = li3[e];
            INS8(s, gi);
        }
        size_t o = (size_t)(q * 8 + c) * TOPK;
#pragma unroll
        for (int r = 0; r < 8; ++r) { cs[o + r] = ts[r]; ci[o + r] = ti[r]; }
    }
}

// stage B: final merge (64 candidates), softmax, gather+fuse
__global__ __launch_bounds__(256) void merge_b_kernel(
        const float* __restrict__ docs, const float* __restrict__ cs,
        const int* __restrict__ ci, float* __restrict__ out) {
    const int q = blockIdx.x;
    const int tid = threadIdx.x;
    __shared__ int   fi[TOPK];
    __shared__ float wr[TOPK];

    if (tid == 0) {
        float ts[8]; int ti[8];
#pragma unroll
        for (int r = 0; r < 8; ++r) { ts[r] = -3.402823466e38f; ti[r] = 0x7fffffff; }
        for (int e = 0; e < 64; ++e) {
            float s = cs[q * 64 + e]; int gi = ci[q * 64 + e];
            INS8(s, gi);
        }
        float m = ts[0];
        float w[8]; float sum = 0.f;
#pragma unroll
        for (int r = 0; r < 8; ++r) { w[r] = expf(ts[r] - m); sum += w[r]; }
        float rs = 1.0f / sum;
#pragma unroll
        for (int r = 0; r < 8; ++r) {
            fi[r] = ti[r];
            wr[r] = w[r] * rs;
            out[BATCH * EMBED + q * TOPK + r] = ts[r];
            out[BATCH * EMBED + BATCH * TOPK + q * TOPK + r] = (float)ti[r];
        }
    }
    __syncthreads();

    int lane = tid & 63, wave = tid >> 6;
    for (int r = wave; r < TOPK; r += 4) {
        const float* dp = docs + (size_t)fi[r] * EMBED;
        float s = 0.f;
#pragma unroll
        for (int i = 0; i < 6; ++i) { float v = dp[lane + 64 * i]; s = fmaf(v, v, s); }
#pragma unroll
        for (int off = 32; off > 0; off >>= 1) s += __shfl_xor(s, off);
        if (lane == 0) wr[r] = wr[r] / (sqrtf(s) + EPSN);
    }
    __syncthreads();

    for (int dim = tid; dim < EMBED; dim += 256) {
        float a = 0.f;
#pragma unroll
        for (int r = 0; r < 8; ++r)
            a += wr[r] * docs[(size_t)fi[r] * EMBED + dim];
        out[q * EMBED + dim] = a;
    }
}

extern "C" void kernel_launch(void* const* d_in, const int* in_sizes, int n_in,
                              void* d_out, int out_size, void* d_ws, size_t ws_size,
                              hipStream_t stream) {
    const float* query = (const float*)d_in[0];
    const float* docs  = (const float*)d_in[1];
    float* out = (float*)d_out;

    char* ws = (char*)d_ws;
    unsigned short* qh = (unsigned short*)ws;                       // 48 KiB
    unsigned short* ql = (unsigned short*)(ws + 49152);             // 48 KiB
    float* pscore = (float*)(ws + 98304);                           // 4 MiB
    int*   pidx   = (int*)(ws + 98304 + (size_t)NBLK * BATCH * TOPK * 4);
    char*  ws3    = ws + 98304 + 2 * (size_t)NBLK * BATCH * TOPK * 4;
    float* cs     = (float*)ws3;                                    // 16 KiB
    int*   ci     = (int*)(ws3 + BATCH * 8 * TOPK * 4);

    qprep_kernel<<<64, 64, 0, stream>>>(query, qh, ql);
    score_topk_kernel<<<256, 512, 0, stream>>>(docs, qh, ql, pscore, pidx);
    merge_a_kernel<<<BATCH * 8, 256, 0, stream>>>(pscore, pidx, cs, ci);
    merge_b_kernel<<<BATCH, 256, 0, stream>>>(docs, cs, ci, out);
}